// Round 1
// baseline (142.168 us; speedup 1.0000x reference)
//
#include <hip/hip_runtime.h>
#include <hip/hip_bf16.h>
#include <math.h>

// Problem constants (fixed by setup_inputs)
#define EDGES   32768
#define NPTS    32768
#define IMGH    256
#define CIN     62
#define CH      64     // channels in conv stack (62 image + 2 coord)
#define L0      32768  // conv0 input length
#define L1      16384
#define L2      8192
#define L3      4096

// ---------------------------------------------------------------------------
// Kernel 1: weight pre-transpose  W[o][i][k] (64x64x3) -> Wt[(i*3+k)][o] (192x64)
// for all three layers concatenated.
// ---------------------------------------------------------------------------
__global__ void wprep_k(const float* __restrict__ W0, const float* __restrict__ W1,
                        const float* __restrict__ W2, float* __restrict__ Wt)
{
    int idx = blockIdx.x * 256 + threadIdx.x;   // 3 * 192 * 64 = 36864
    if (idx >= 3 * 192 * 64) return;
    int l   = idx / 12288;
    int rem = idx - l * 12288;
    int row = rem >> 6;          // i*3+k
    int o   = rem & 63;
    int i   = row / 3;
    int k   = row - i * 3;
    const float* W = (l == 0) ? W0 : ((l == 1) ? W1 : W2);
    Wt[idx] = W[o * 192 + i * 3 + k];
}

// ---------------------------------------------------------------------------
// Kernel 2: edge lengths + inclusive cumsum in f64 (matches np f64 reference
// to ~1e-15; parallel-scan reassociation is irrelevant at f64 precision).
// 1024 threads x 32 edges each.
// ---------------------------------------------------------------------------
__global__ __launch_bounds__(1024) void scan_k(const float* __restrict__ corners,
                                               double* __restrict__ el2)
{
    __shared__ double tot[1024];
    int t = threadIdx.x;
    int base = t << 5;
    double s = 0.0;
    for (int m = 0; m < 32; ++m) {
        int e  = base + m;
        int en = (e + 1) & (EDGES - 1);
        double dx = (double)corners[2 * en]     - (double)corners[2 * e];
        double dy = (double)corners[2 * en + 1] - (double)corners[2 * e + 1];
        s += sqrt(dx * dx + dy * dy);
    }
    tot[t] = s;
    __syncthreads();
    // Hillis-Steele inclusive scan over 1024 partials
    for (int o = 1; o < 1024; o <<= 1) {
        double v = (t >= o) ? tot[t - o] : 0.0;
        __syncthreads();
        tot[t] += v;
        __syncthreads();
    }
    double run = (t == 0) ? 0.0 : tot[t - 1];
    for (int m = 0; m < 32; ++m) {
        int e  = base + m;
        int en = (e + 1) & (EDGES - 1);
        double dx = (double)corners[2 * en]     - (double)corners[2 * e];
        double dy = (double)corners[2 * en + 1] - (double)corners[2 * e + 1];
        run += sqrt(dx * dx + dy * dy);
        el2[e] = run;
    }
}

// ---------------------------------------------------------------------------
// Kernel 3: image transpose (C,H,H) -> (H*H, 64)  [channels 62,63 zeroed]
// so the point-gather reads 62 contiguous floats instead of 62 strided lines.
// ---------------------------------------------------------------------------
__global__ __launch_bounds__(256) void transpose_k(const float* __restrict__ img,
                                                   float* __restrict__ imgT)
{
    __shared__ float tile[CIN][65];
    int pix0 = blockIdx.x << 6;   // 64 pixels per block
    int tid  = threadIdx.x;
    for (int idx = tid; idx < CIN * 64; idx += 256) {
        int c = idx >> 6, p = idx & 63;
        tile[c][p] = img[c * (IMGH * IMGH) + pix0 + p];
    }
    __syncthreads();
    for (int idx = tid; idx < 64 * 64; idx += 256) {
        int p = idx >> 6, c = idx & 63;
        imgT[(size_t)(pix0 + p) * 64 + c] = (c < CIN) ? tile[c][p] : 0.f;
    }
}

// ---------------------------------------------------------------------------
// Kernel 4: per-point arc-length placement (binary search over el2) + gather.
// All geometry in f64. Writes X (64 x NPTS): 62 image channels + px + py.
// ---------------------------------------------------------------------------
__global__ __launch_bounds__(256) void gather_k(const float* __restrict__ corners,
                                                const double* __restrict__ el2,
                                                const float* __restrict__ imgT,
                                                float* __restrict__ X)
{
    int p = blockIdx.x * 256 + threadIdx.x;
    double S   = el2[EDGES - 1];
    double off = (double)p * (S * (1.0 / (double)NPTS));
    // lower_bound: first e with el2[e] > off  (== the reference's one-hot mask)
    int lo = 0, hi = EDGES - 1;
    while (lo < hi) {
        int mid = (lo + hi) >> 1;
        if (el2[mid] > off) hi = mid; else lo = mid + 1;
    }
    int e = lo;
    double e1 = (e == 0) ? 0.0 : el2[e - 1];
    float sxf = corners[2 * e], syf = corners[2 * e + 1];
    int en = (e + 1) & (EDGES - 1);
    double dx = (double)corners[2 * en]     - (double)sxf;
    double dy = (double)corners[2 * en + 1] - (double)syf;
    double len = sqrt(dx * dx + dy * dy);
    double t = (off - e1) / fmax(len, 0.0001);
    double px = (double)sxf + t * dx;
    double py = (double)syf + t * dy;
    int r0 = (int)rint(px * (double)IMGH); r0 = r0 < 0 ? 0 : (r0 > IMGH - 1 ? IMGH - 1 : r0);
    int r1 = (int)rint(py * (double)IMGH); r1 = r1 < 0 ? 0 : (r1 > IMGH - 1 ? IMGH - 1 : r1);
    const float* row = imgT + (size_t)((r0 << 8) | r1) * 64;
    const float4* row4 = (const float4*)row;
#pragma unroll
    for (int c4 = 0; c4 < 15; ++c4) {      // channels 0..59
        float4 v = row4[c4];
        X[(c4 * 4 + 0) * NPTS + p] = v.x;
        X[(c4 * 4 + 1) * NPTS + p] = v.y;
        X[(c4 * 4 + 2) * NPTS + p] = v.z;
        X[(c4 * 4 + 3) * NPTS + p] = v.w;
    }
    X[60 * NPTS + p] = row[60];
    X[61 * NPTS + p] = row[61];
    X[62 * NPTS + p] = (float)px;
    X[63 * NPTS + p] = (float)py;
}

// ---------------------------------------------------------------------------
// Kernel 5: conv1d block: reflect-pad(1,1), k=3, stride 2, +bias, relu.
// Block = 64 output positions x 64 output channels (256 thr = 4 waves).
// Wave w owns output channels [16w,16w+16): weight loads are wave-uniform.
// Input tile staged in LDS (64 ch x 130 pos).
// Wt layout: [(i*3+k)*64 + o].
// ---------------------------------------------------------------------------
__global__ __launch_bounds__(256) void conv_k(const float* __restrict__ Xin,
                                              const float* __restrict__ Wt,
                                              const float* __restrict__ bias,
                                              float* __restrict__ Yout,
                                              int Lin, int Lout)
{
    __shared__ float xs[64][130];
    int tid = threadIdx.x;
    int j0  = blockIdx.x << 6;
    int in0 = (j0 << 1) - 1;
    for (int idx = tid; idx < 64 * 130; idx += 256) {
        int i  = idx / 130;
        int pp = idx - i * 130;
        int g  = in0 + pp;
        if (g < 0)    g = 1;               // reflect left: -1 -> 1
        if (g >= Lin) g = 2 * Lin - 2 - g; // guard only (value unused)
        xs[i][pp] = Xin[i * Lin + g];
    }
    __syncthreads();

    int lane = tid & 63;
    int o0   = (tid >> 6) << 4;
    o0 = __builtin_amdgcn_readfirstlane(o0);   // force wave-uniform weight addressing

    float acc[16];
#pragma unroll
    for (int m = 0; m < 16; ++m) acc[m] = bias[o0 + m];

    int jl2 = lane << 1;
    for (int i = 0; i < 64; ++i) {
        float x0 = xs[i][jl2];
        float x1 = xs[i][jl2 + 1];
        float x2 = xs[i][jl2 + 2];
        const float4* w0 = (const float4*)(Wt + (i * 3 + 0) * 64 + o0);
        const float4* w1 = (const float4*)(Wt + (i * 3 + 1) * 64 + o0);
        const float4* w2 = (const float4*)(Wt + (i * 3 + 2) * 64 + o0);
#pragma unroll
        for (int q = 0; q < 4; ++q) {
            float4 a = w0[q], b = w1[q], c = w2[q];
            acc[q * 4 + 0] = fmaf(a.x, x0, fmaf(b.x, x1, fmaf(c.x, x2, acc[q * 4 + 0])));
            acc[q * 4 + 1] = fmaf(a.y, x0, fmaf(b.y, x1, fmaf(c.y, x2, acc[q * 4 + 1])));
            acc[q * 4 + 2] = fmaf(a.z, x0, fmaf(b.z, x1, fmaf(c.z, x2, acc[q * 4 + 2])));
            acc[q * 4 + 3] = fmaf(a.w, x0, fmaf(b.w, x1, fmaf(c.w, x2, acc[q * 4 + 3])));
        }
    }
    int j = j0 + lane;
#pragma unroll
    for (int m = 0; m < 16; ++m)
        Yout[(o0 + m) * Lout + j] = fmaxf(acc[m], 0.f);
}

// ---------------------------------------------------------------------------
// Kernel 6: per-channel max over positions (relu already applied upstream).
// One block per channel.
// ---------------------------------------------------------------------------
__global__ __launch_bounds__(256) void rowmax_k(const float* __restrict__ Y,
                                                float* __restrict__ cmax)
{
    __shared__ float red[256];
    int c = blockIdx.x, tid = threadIdx.x;
    float m = -1e30f;
    for (int j = tid; j < L3; j += 256) m = fmaxf(m, Y[c * L3 + j]);
    red[tid] = m;
    __syncthreads();
    for (int o = 128; o > 0; o >>= 1) {
        if (tid < o) red[tid] = fmaxf(red[tid], red[tid + o]);
        __syncthreads();
    }
    if (tid == 0) cmax[c] = red[0];
}

// ---------------------------------------------------------------------------
// Kernel 7: feat = relu(cmax @ Wf^T + bf);  pred = sigmoid(feat @ Wp^T + bp)
// d_out = [feat(64), pred(1)]
// ---------------------------------------------------------------------------
__global__ __launch_bounds__(64) void fc_k(const float* __restrict__ cmax,
                                           const float* __restrict__ Wf,
                                           const float* __restrict__ bf,
                                           const float* __restrict__ Wp,
                                           const float* __restrict__ bp,
                                           float* __restrict__ out)
{
    __shared__ float cm[64];
    __shared__ float ft[64];
    int t = threadIdx.x;
    cm[t] = cmax[t];
    __syncthreads();
    float s = bf[t];
#pragma unroll
    for (int c = 0; c < 64; ++c) s = fmaf(Wf[t * 64 + c], cm[c], s);
    float f = fmaxf(s, 0.f);
    ft[t] = f;
    out[t] = f;
    __syncthreads();
    if (t == 0) {
        float z = bp[0];
#pragma unroll
        for (int c = 0; c < 64; ++c) z = fmaf(Wp[c], ft[c], z);
        out[64] = 1.f / (1.f + expf(-z));
    }
}

// ---------------------------------------------------------------------------
extern "C" void kernel_launch(void* const* d_in, const int* in_sizes, int n_in,
                              void* d_out, int out_size, void* d_ws, size_t ws_size,
                              hipStream_t stream)
{
    const float* image   = (const float*)d_in[0];
    const float* corners = (const float*)d_in[1];
    const float* W0      = (const float*)d_in[2];
    const float* b0      = (const float*)d_in[3];
    const float* W1      = (const float*)d_in[4];
    const float* b1      = (const float*)d_in[5];
    const float* W2      = (const float*)d_in[6];
    const float* b2      = (const float*)d_in[7];
    const float* Wf      = (const float*)d_in[8];
    const float* bf      = (const float*)d_in[9];
    const float* Wp      = (const float*)d_in[10];
    const float* bp      = (const float*)d_in[11];
    float* out = (float*)d_out;

    // workspace layout (all 256B-aligned); total ~33 MB
    char* w = (char*)d_ws;
    double* el2  = (double*)(w);                 // 32768*8   = 262144
    float*  Wt   = (float*) (w + 262144);        // 3*192*64*4= 147456 -> 409600
    float*  imgT = (float*) (w + 409600);        // 65536*64*4= 16777216 -> 17186816
    float*  X    = (float*) (w + 17186816);      // 64*32768*4= 8388608 -> 25575424
    float*  Y0   = (float*) (w + 25575424);      // 64*16384*4= 4194304 -> 29769728
    float*  Y1   = (float*) (w + 29769728);      // 64*8192*4 = 2097152 -> 31866880
    float*  Y2   = (float*) (w + 31866880);      // 64*4096*4 = 1048576 -> 32915456
    float*  cmax = (float*) (w + 32915456);      // 64*4

    wprep_k    <<<144, 256, 0, stream>>>(W0, W1, W2, Wt);
    scan_k     <<<1, 1024, 0, stream>>>(corners, el2);
    transpose_k<<<(IMGH * IMGH) / 64, 256, 0, stream>>>(image, imgT);
    gather_k   <<<NPTS / 256, 256, 0, stream>>>(corners, el2, imgT, X);
    conv_k     <<<L1 / 64, 256, 0, stream>>>(X,  Wt,            b0, Y0, L0, L1);
    conv_k     <<<L2 / 64, 256, 0, stream>>>(Y0, Wt + 12288,    b1, Y1, L1, L2);
    conv_k     <<<L3 / 64, 256, 0, stream>>>(Y1, Wt + 2*12288,  b2, Y2, L2, L3);
    rowmax_k   <<<64, 256, 0, stream>>>(Y2, cmax);
    fc_k       <<<1, 64, 0, stream>>>(cmax, Wf, bf, Wp, bp, out);
}

// Round 2
// 115.181 us; speedup vs baseline: 1.2343x; 1.2343x over previous
//
#include <hip/hip_runtime.h>
#include <hip/hip_bf16.h>
#include <math.h>

// Problem constants (fixed by setup_inputs)
#define EDGES   32768
#define NPTS    32768
#define IMGH    256
#define L0      32768  // conv0 input length
#define L1      16384
#define L2      8192
#define L3      4096

// ---------------------------------------------------------------------------
// Kernel 1 (fused prep): block-range dispatch over one grid of 648x512.
//   blocks   0..63  : edge lengths (f64) + in-block inclusive scan of 512
//                     -> el2loc (local cumsum) + partial[block]
//   blocks  64..135 : weight transpose W[o][i][k] -> Wt[(i*3+k)*64+o] (x3 layers)
//   blocks 136..647 : image transpose (62,256,256) -> (65536,64), ch 62/63 = 0
// ---------------------------------------------------------------------------
__global__ __launch_bounds__(512) void prep_k(const float* __restrict__ corners,
                                              const float* __restrict__ W0,
                                              const float* __restrict__ W1,
                                              const float* __restrict__ W2,
                                              const float* __restrict__ img,
                                              double* __restrict__ el2loc,
                                              double* __restrict__ partial,
                                              float*  __restrict__ Wt,
                                              float*  __restrict__ imgT)
{
    __shared__ union { double sc[512]; float tile[62][129]; } sm;
    int b = blockIdx.x, t = threadIdx.x;
    if (b < 64) {
        int e  = (b << 9) + t;
        int en = (e + 1) & (EDGES - 1);
        double dx = (double)corners[2*en]   - (double)corners[2*e];
        double dy = (double)corners[2*en+1] - (double)corners[2*e+1];
        sm.sc[t] = sqrt(dx*dx + dy*dy);
        __syncthreads();
        for (int o = 1; o < 512; o <<= 1) {        // Hillis-Steele inclusive
            double v = (t >= o) ? sm.sc[t - o] : 0.0;
            __syncthreads();
            sm.sc[t] += v;
            __syncthreads();
        }
        el2loc[e] = sm.sc[t];
        if (t == 511) partial[b] = sm.sc[511];
    } else if (b < 136) {
        int idx = ((b - 64) << 9) + t;             // < 3*192*64 = 36864
        int l   = idx / 12288;
        int rem = idx - l * 12288;
        int row = rem >> 6, o = rem & 63;
        int i   = row / 3,  k = row - i * 3;
        const float* W = (l == 0) ? W0 : ((l == 1) ? W1 : W2);
        Wt[idx] = W[o*192 + i*3 + k];
    } else {
        int pix0 = (b - 136) << 7;                 // 128 pixels per block
        for (int idx = t; idx < 62*128; idx += 512) {
            int c = idx >> 7, p = idx & 127;
            sm.tile[c][p] = img[c * (IMGH*IMGH) + pix0 + p];
        }
        __syncthreads();
        for (int idx = t; idx < 128*64; idx += 512) {
            int p = idx >> 6, c = idx & 63;
            imgT[(size_t)(pix0 + p) * 64 + c] = (c < 62) ? sm.tile[c][p] : 0.f;
        }
    }
}

// ---------------------------------------------------------------------------
// Kernel 2: scan the 64 block partials (inclusive) -> boff; zero cmax for the
// conv2 atomic-max (runs before conv_last_k in stream order).
// ---------------------------------------------------------------------------
__global__ __launch_bounds__(64) void scan2_k(const double* __restrict__ partial,
                                              double* __restrict__ boff,
                                              float* __restrict__ cmax)
{
    __shared__ double s[64];
    int t = threadIdx.x;
    s[t] = partial[t];
    cmax[t] = 0.f;
    __syncthreads();
    for (int o = 1; o < 64; o <<= 1) {
        double v = (t >= o) ? s[t - o] : 0.0;
        __syncthreads();
        s[t] += v;
        __syncthreads();
    }
    boff[t] = s[t];
}

// ---------------------------------------------------------------------------
// Kernel 3: per-point arc-length placement + gather.
// Global cumsum composed on the fly: el2g(e) = el2loc[e] + boff[(e>>9)-1].
// ---------------------------------------------------------------------------
__global__ __launch_bounds__(256) void gather_k(const float* __restrict__ corners,
                                                const double* __restrict__ el2loc,
                                                const double* __restrict__ boff,
                                                const float* __restrict__ imgT,
                                                float* __restrict__ X)
{
    __shared__ double sb[64];
    int tid = threadIdx.x;
    if (tid < 64) sb[tid] = boff[tid];
    __syncthreads();

    int p = blockIdx.x * 256 + tid;
    double S   = sb[63];
    double off = (double)p * (S * (1.0 / (double)NPTS));
    // lower_bound: first e with el2g(e) > off
    int lo = 0, hi = EDGES - 1;
    while (lo < hi) {
        int mid = (lo + hi) >> 1;
        double v = el2loc[mid] + ((mid >= 512) ? sb[(mid >> 9) - 1] : 0.0);
        if (v > off) hi = mid; else lo = mid + 1;
    }
    int e = lo;
    double e1 = (e == 0) ? 0.0
              : el2loc[e-1] + (((e-1) >= 512) ? sb[((e-1) >> 9) - 1] : 0.0);
    float sxf = corners[2*e], syf = corners[2*e+1];
    int en = (e + 1) & (EDGES - 1);
    double dx = (double)corners[2*en]   - (double)sxf;
    double dy = (double)corners[2*en+1] - (double)syf;
    double len = sqrt(dx*dx + dy*dy);
    double t = (off - e1) / fmax(len, 0.0001);
    double px = (double)sxf + t * dx;
    double py = (double)syf + t * dy;
    int r0 = (int)rint(px * (double)IMGH); r0 = r0 < 0 ? 0 : (r0 > IMGH-1 ? IMGH-1 : r0);
    int r1 = (int)rint(py * (double)IMGH); r1 = r1 < 0 ? 0 : (r1 > IMGH-1 ? IMGH-1 : r1);
    const float*  row  = imgT + (size_t)((r0 << 8) | r1) * 64;
    const float4* row4 = (const float4*)row;
#pragma unroll
    for (int c4 = 0; c4 < 15; ++c4) {      // channels 0..59
        float4 v = row4[c4];
        X[(c4*4 + 0) * NPTS + p] = v.x;
        X[(c4*4 + 1) * NPTS + p] = v.y;
        X[(c4*4 + 2) * NPTS + p] = v.z;
        X[(c4*4 + 3) * NPTS + p] = v.w;
    }
    X[60 * NPTS + p] = row[60];
    X[61 * NPTS + p] = row[61];
    X[62 * NPTS + p] = (float)px;
    X[63 * NPTS + p] = (float)py;
}

// ---------------------------------------------------------------------------
// Kernel 4: conv1d block (layers 0,1): reflect pad(1,1), k=3, stride 2, relu.
// Block = 64 out pos x 64 out ch (4 waves); wave owns 16 channels (uniform
// weight addressing). Input tile in LDS.
// ---------------------------------------------------------------------------
__global__ __launch_bounds__(256) void conv_k(const float* __restrict__ Xin,
                                              const float* __restrict__ Wt,
                                              const float* __restrict__ bias,
                                              float* __restrict__ Yout,
                                              int Lin, int Lout)
{
    __shared__ float xs[64][130];
    int tid = threadIdx.x;
    int j0  = blockIdx.x << 6;
    int in0 = (j0 << 1) - 1;
    for (int idx = tid; idx < 64 * 130; idx += 256) {
        int i  = idx / 130;
        int pp = idx - i * 130;
        int g  = in0 + pp;
        if (g < 0)    g = 1;
        if (g >= Lin) g = 2 * Lin - 2 - g;   // guard only (value unused)
        xs[i][pp] = Xin[i * Lin + g];
    }
    __syncthreads();

    int lane = tid & 63;
    int o0   = (tid >> 6) << 4;
    o0 = __builtin_amdgcn_readfirstlane(o0);

    float acc[16];
#pragma unroll
    for (int m = 0; m < 16; ++m) acc[m] = bias[o0 + m];

    int jl2 = lane << 1;
    for (int i = 0; i < 64; ++i) {
        float x0 = xs[i][jl2];
        float x1 = xs[i][jl2 + 1];
        float x2 = xs[i][jl2 + 2];
        const float4* w0 = (const float4*)(Wt + (i*3 + 0) * 64 + o0);
        const float4* w1 = (const float4*)(Wt + (i*3 + 1) * 64 + o0);
        const float4* w2 = (const float4*)(Wt + (i*3 + 2) * 64 + o0);
#pragma unroll
        for (int q = 0; q < 4; ++q) {
            float4 a = w0[q], b = w1[q], c = w2[q];
            acc[q*4+0] = fmaf(a.x, x0, fmaf(b.x, x1, fmaf(c.x, x2, acc[q*4+0])));
            acc[q*4+1] = fmaf(a.y, x0, fmaf(b.y, x1, fmaf(c.y, x2, acc[q*4+1])));
            acc[q*4+2] = fmaf(a.z, x0, fmaf(b.z, x1, fmaf(c.z, x2, acc[q*4+2])));
            acc[q*4+3] = fmaf(a.w, x0, fmaf(b.w, x1, fmaf(c.w, x2, acc[q*4+3])));
        }
    }
    int j = j0 + lane;
#pragma unroll
    for (int m = 0; m < 16; ++m)
        Yout[(o0 + m) * Lout + j] = fmaxf(acc[m], 0.f);
}

// ---------------------------------------------------------------------------
// Kernel 5: conv layer 2 fused with the global max-pool: instead of writing
// Y2, butterfly-max relu(acc) across the wave's 64 positions and atomicMax
// into cmax (float-as-int valid: all values >= 0; cmax zeroed by scan2_k).
// ---------------------------------------------------------------------------
__global__ __launch_bounds__(256) void conv_last_k(const float* __restrict__ Xin,
                                                   const float* __restrict__ Wt,
                                                   const float* __restrict__ bias,
                                                   float* __restrict__ cmax,
                                                   int Lin, int Lout)
{
    __shared__ float xs[64][130];
    int tid = threadIdx.x;
    int j0  = blockIdx.x << 6;
    int in0 = (j0 << 1) - 1;
    for (int idx = tid; idx < 64 * 130; idx += 256) {
        int i  = idx / 130;
        int pp = idx - i * 130;
        int g  = in0 + pp;
        if (g < 0)    g = 1;
        if (g >= Lin) g = 2 * Lin - 2 - g;
        xs[i][pp] = Xin[i * Lin + g];
    }
    __syncthreads();

    int lane = tid & 63;
    int o0   = (tid >> 6) << 4;
    o0 = __builtin_amdgcn_readfirstlane(o0);

    float acc[16];
#pragma unroll
    for (int m = 0; m < 16; ++m) acc[m] = bias[o0 + m];

    int jl2 = lane << 1;
    for (int i = 0; i < 64; ++i) {
        float x0 = xs[i][jl2];
        float x1 = xs[i][jl2 + 1];
        float x2 = xs[i][jl2 + 2];
        const float4* w0 = (const float4*)(Wt + (i*3 + 0) * 64 + o0);
        const float4* w1 = (const float4*)(Wt + (i*3 + 1) * 64 + o0);
        const float4* w2 = (const float4*)(Wt + (i*3 + 2) * 64 + o0);
#pragma unroll
        for (int q = 0; q < 4; ++q) {
            float4 a = w0[q], b = w1[q], c = w2[q];
            acc[q*4+0] = fmaf(a.x, x0, fmaf(b.x, x1, fmaf(c.x, x2, acc[q*4+0])));
            acc[q*4+1] = fmaf(a.y, x0, fmaf(b.y, x1, fmaf(c.y, x2, acc[q*4+1])));
            acc[q*4+2] = fmaf(a.z, x0, fmaf(b.z, x1, fmaf(c.z, x2, acc[q*4+2])));
            acc[q*4+3] = fmaf(a.w, x0, fmaf(b.w, x1, fmaf(c.w, x2, acc[q*4+3])));
        }
    }
#pragma unroll
    for (int m = 0; m < 16; ++m) {
        float v = fmaxf(acc[m], 0.f);
#pragma unroll
        for (int off = 1; off < 64; off <<= 1)
            v = fmaxf(v, __shfl_xor(v, off));
        if (lane == 0)
            atomicMax((int*)&cmax[o0 + m], __float_as_int(v));
    }
}

// ---------------------------------------------------------------------------
// Kernel 6: feat = relu(cmax @ Wf^T + bf);  pred = sigmoid(feat @ Wp^T + bp)
// ---------------------------------------------------------------------------
__global__ __launch_bounds__(64) void fc_k(const float* __restrict__ cmax,
                                           const float* __restrict__ Wf,
                                           const float* __restrict__ bf,
                                           const float* __restrict__ Wp,
                                           const float* __restrict__ bp,
                                           float* __restrict__ out)
{
    __shared__ float cm[64];
    __shared__ float ft[64];
    int t = threadIdx.x;
    cm[t] = cmax[t];
    __syncthreads();
    float s = bf[t];
#pragma unroll
    for (int c = 0; c < 64; ++c) s = fmaf(Wf[t*64 + c], cm[c], s);
    float f = fmaxf(s, 0.f);
    ft[t] = f;
    out[t] = f;
    __syncthreads();
    if (t == 0) {
        float z = bp[0];
#pragma unroll
        for (int c = 0; c < 64; ++c) z = fmaf(Wp[c], ft[c], z);
        out[64] = 1.f / (1.f + expf(-z));
    }
}

// ---------------------------------------------------------------------------
extern "C" void kernel_launch(void* const* d_in, const int* in_sizes, int n_in,
                              void* d_out, int out_size, void* d_ws, size_t ws_size,
                              hipStream_t stream)
{
    const float* image   = (const float*)d_in[0];
    const float* corners = (const float*)d_in[1];
    const float* W0      = (const float*)d_in[2];
    const float* b0      = (const float*)d_in[3];
    const float* W1      = (const float*)d_in[4];
    const float* b1      = (const float*)d_in[5];
    const float* W2      = (const float*)d_in[6];
    const float* b2      = (const float*)d_in[7];
    const float* Wf      = (const float*)d_in[8];
    const float* bf      = (const float*)d_in[9];
    const float* Wp      = (const float*)d_in[10];
    const float* bp      = (const float*)d_in[11];
    float* out = (float*)d_out;

    // workspace layout (256B-aligned), ~32 MB total
    char* w = (char*)d_ws;
    double* el2loc  = (double*)(w);                 //  262144 B
    double* partial = (double*)(w + 262144);        //     512 B
    double* boff    = (double*)(w + 262656);        //     512 B
    float*  cmax    = (float*) (w + 263168);        //     256 B
    float*  Wt      = (float*) (w + 263424);        //  147456 B
    float*  imgT    = (float*) (w + 410880);        // 16777216 B
    float*  X       = (float*) (w + 17188096);      // 8388608 B
    float*  Y0      = (float*) (w + 25576704);      // 4194304 B
    float*  Y1      = (float*) (w + 29771008);      // 2097152 B -> end 31868160

    prep_k     <<<648, 512, 0, stream>>>(corners, W0, W1, W2, image,
                                         el2loc, partial, Wt, imgT);
    scan2_k    <<<1, 64, 0, stream>>>(partial, boff, cmax);
    gather_k   <<<NPTS / 256, 256, 0, stream>>>(corners, el2loc, boff, imgT, X);
    conv_k     <<<L1 / 64, 256, 0, stream>>>(X,  Wt,           b0, Y0, L0, L1);
    conv_k     <<<L2 / 64, 256, 0, stream>>>(Y0, Wt + 12288,   b1, Y1, L1, L2);
    conv_last_k<<<L3 / 64, 256, 0, stream>>>(Y1, Wt + 2*12288, b2, cmax, L2, L3);
    fc_k       <<<1, 64, 0, stream>>>(cmax, Wf, bf, Wp, bp, out);
}

// Round 3
// 84.701 us; speedup vs baseline: 1.6785x; 1.3599x over previous
//
#include <hip/hip_runtime.h>
#include <hip/hip_bf16.h>
#include <math.h>

// Problem constants (fixed by setup_inputs)
#define EDGES   32768
#define NPTS    32768
#define IMGH    256
#define L0      32768  // conv0 input length
#define L1      16384
#define L2      8192
#define L3      4096
#define NB2     64     // blocks in last conv (= L3/64)

// ---------------------------------------------------------------------------
// Kernel 1 (fused prep): block-range dispatch over one grid of 648x512.
//   blocks   0..63  : edge lengths (f64) + in-block inclusive scan of 512
//   blocks  64..135 : weight transpose W[o][i][k] -> Wt[(i*3+k)*64+o] (x3)
//   blocks 136..647 : image transpose (62,256,256) -> (65536,64), ch 62/63 = 0
// ---------------------------------------------------------------------------
__global__ __launch_bounds__(512) void prep_k(const float* __restrict__ corners,
                                              const float* __restrict__ W0,
                                              const float* __restrict__ W1,
                                              const float* __restrict__ W2,
                                              const float* __restrict__ img,
                                              double* __restrict__ el2loc,
                                              double* __restrict__ partial,
                                              float*  __restrict__ Wt,
                                              float*  __restrict__ imgT)
{
    __shared__ union { double sc[512]; float tile[62][129]; } sm;
    int b = blockIdx.x, t = threadIdx.x;
    if (b < 64) {
        int e  = (b << 9) + t;
        int en = (e + 1) & (EDGES - 1);
        double dx = (double)corners[2*en]   - (double)corners[2*e];
        double dy = (double)corners[2*en+1] - (double)corners[2*e+1];
        sm.sc[t] = sqrt(dx*dx + dy*dy);
        __syncthreads();
        for (int o = 1; o < 512; o <<= 1) {        // Hillis-Steele inclusive
            double v = (t >= o) ? sm.sc[t - o] : 0.0;
            __syncthreads();
            sm.sc[t] += v;
            __syncthreads();
        }
        el2loc[e] = sm.sc[t];
        if (t == 511) partial[b] = sm.sc[511];
    } else if (b < 136) {
        int idx = ((b - 64) << 9) + t;             // < 3*192*64 = 36864
        int l   = idx / 12288;
        int rem = idx - l * 12288;
        int row = rem >> 6, o = rem & 63;
        int i   = row / 3,  k = row - i * 3;
        const float* W = (l == 0) ? W0 : ((l == 1) ? W1 : W2);
        Wt[idx] = W[o*192 + i*3 + k];
    } else {
        int pix0 = (b - 136) << 7;                 // 128 pixels per block
        for (int idx = t; idx < 62*128; idx += 512) {
            int c = idx >> 7, p = idx & 127;
            sm.tile[c][p] = img[c * (IMGH*IMGH) + pix0 + p];
        }
        __syncthreads();
        for (int idx = t; idx < 128*64; idx += 512) {
            int p = idx >> 6, c = idx & 63;
            imgT[(size_t)(pix0 + p) * 64 + c] = (c < 62) ? sm.tile[c][p] : 0.f;
        }
    }
}

// ---------------------------------------------------------------------------
// Kernel 2: scan the 64 block partials (inclusive) -> boff.
// ---------------------------------------------------------------------------
__global__ __launch_bounds__(64) void scan2_k(const double* __restrict__ partial,
                                              double* __restrict__ boff)
{
    __shared__ double s[64];
    int t = threadIdx.x;
    s[t] = partial[t];
    __syncthreads();
    for (int o = 1; o < 64; o <<= 1) {
        double v = (t >= o) ? s[t - o] : 0.0;
        __syncthreads();
        s[t] += v;
        __syncthreads();
    }
    boff[t] = s[t];
}

// ---------------------------------------------------------------------------
// Kernel 3: per-point arc-length placement + gather.
// Global cumsum composed on the fly: el2g(e) = el2loc[e] + boff[(e>>9)-1].
// ---------------------------------------------------------------------------
__global__ __launch_bounds__(256) void gather_k(const float* __restrict__ corners,
                                                const double* __restrict__ el2loc,
                                                const double* __restrict__ boff,
                                                const float* __restrict__ imgT,
                                                float* __restrict__ X)
{
    __shared__ double sb[64];
    int tid = threadIdx.x;
    if (tid < 64) sb[tid] = boff[tid];
    __syncthreads();

    int p = blockIdx.x * 256 + tid;
    double S   = sb[63];
    double off = (double)p * (S * (1.0 / (double)NPTS));
    int lo = 0, hi = EDGES - 1;
    while (lo < hi) {
        int mid = (lo + hi) >> 1;
        double v = el2loc[mid] + ((mid >= 512) ? sb[(mid >> 9) - 1] : 0.0);
        if (v > off) hi = mid; else lo = mid + 1;
    }
    int e = lo;
    double e1 = (e == 0) ? 0.0
              : el2loc[e-1] + (((e-1) >= 512) ? sb[((e-1) >> 9) - 1] : 0.0);
    float sxf = corners[2*e], syf = corners[2*e+1];
    int en = (e + 1) & (EDGES - 1);
    double dx = (double)corners[2*en]   - (double)sxf;
    double dy = (double)corners[2*en+1] - (double)syf;
    double len = sqrt(dx*dx + dy*dy);
    double t = (off - e1) / fmax(len, 0.0001);
    double px = (double)sxf + t * dx;
    double py = (double)syf + t * dy;
    int r0 = (int)rint(px * (double)IMGH); r0 = r0 < 0 ? 0 : (r0 > IMGH-1 ? IMGH-1 : r0);
    int r1 = (int)rint(py * (double)IMGH); r1 = r1 < 0 ? 0 : (r1 > IMGH-1 ? IMGH-1 : r1);
    const float*  row  = imgT + (size_t)((r0 << 8) | r1) * 64;
    const float4* row4 = (const float4*)row;
#pragma unroll
    for (int c4 = 0; c4 < 15; ++c4) {      // channels 0..59
        float4 v = row4[c4];
        X[(c4*4 + 0) * NPTS + p] = v.x;
        X[(c4*4 + 1) * NPTS + p] = v.y;
        X[(c4*4 + 2) * NPTS + p] = v.z;
        X[(c4*4 + 3) * NPTS + p] = v.w;
    }
    X[60 * NPTS + p] = row[60];
    X[61 * NPTS + p] = row[61];
    X[62 * NPTS + p] = (float)px;
    X[63 * NPTS + p] = (float)py;
}

// ---------------------------------------------------------------------------
// Kernel 4: conv1d block: reflect pad(1,1), k=3, stride 2, +bias, relu.
// Block = 64 out pos x 64 out ch (4 waves); wave owns 16 channels.
// Weights staged in LDS in two 96-row chunks (57.8 KB total -> 2 blocks/CU);
// weight reads are wave-uniform LDS broadcasts, i-loop unrolled x4.
// LAST: shuffle-max over the wave's 64 positions -> pmax[block*64+ch].
// ---------------------------------------------------------------------------
template<bool LAST>
__global__ __launch_bounds__(256) void conv_k(const float* __restrict__ Xin,
                                              const float* __restrict__ Wt,
                                              const float* __restrict__ bias,
                                              float* __restrict__ outp,
                                              int Lin)
{
    __shared__ float xs[64][130];   // 33280 B
    __shared__ float ws[96][64];    // 24576 B
    int tid = threadIdx.x;
    int j0  = blockIdx.x << 6;
    int in0 = (j0 << 1) - 1;
    for (int idx = tid; idx < 64 * 130; idx += 256) {
        int i  = idx / 130;
        int pp = idx - i * 130;
        int g  = in0 + pp;
        if (g < 0)    g = 1;               // reflect left
        if (g >= Lin) g = 2 * Lin - 2 - g; // guard (value unused by valid outputs)
        xs[i][pp] = Xin[i * Lin + g];
    }
    {   // weights chunk 0: rows 0..95  (i = 0..31)
        const float4* src = (const float4*)Wt;
        float4*       dst = (float4*)&ws[0][0];
        for (int idx = tid; idx < 96 * 16; idx += 256) dst[idx] = src[idx];
    }
    __syncthreads();

    int lane = tid & 63;
    int o0   = (tid >> 6) << 4;

    float acc[16];
#pragma unroll
    for (int m = 0; m < 16; ++m) acc[m] = bias[o0 + m];

    int jl2 = lane << 1;
#pragma unroll 4
    for (int i = 0; i < 32; ++i) {
        float x0 = xs[i][jl2];
        float x1 = xs[i][jl2 + 1];
        float x2 = xs[i][jl2 + 2];
        const float4* w0 = (const float4*)&ws[i*3 + 0][o0];
        const float4* w1 = (const float4*)&ws[i*3 + 1][o0];
        const float4* w2 = (const float4*)&ws[i*3 + 2][o0];
#pragma unroll
        for (int q = 0; q < 4; ++q) {
            float4 a = w0[q], b = w1[q], c = w2[q];
            acc[q*4+0] = fmaf(a.x, x0, fmaf(b.x, x1, fmaf(c.x, x2, acc[q*4+0])));
            acc[q*4+1] = fmaf(a.y, x0, fmaf(b.y, x1, fmaf(c.y, x2, acc[q*4+1])));
            acc[q*4+2] = fmaf(a.z, x0, fmaf(b.z, x1, fmaf(c.z, x2, acc[q*4+2])));
            acc[q*4+3] = fmaf(a.w, x0, fmaf(b.w, x1, fmaf(c.w, x2, acc[q*4+3])));
        }
    }
    __syncthreads();
    {   // weights chunk 1: rows 96..191  (i = 32..63)
        const float4* src = ((const float4*)Wt) + 96 * 16;
        float4*       dst = (float4*)&ws[0][0];
        for (int idx = tid; idx < 96 * 16; idx += 256) dst[idx] = src[idx];
    }
    __syncthreads();
#pragma unroll 4
    for (int i = 32; i < 64; ++i) {
        float x0 = xs[i][jl2];
        float x1 = xs[i][jl2 + 1];
        float x2 = xs[i][jl2 + 2];
        const float4* w0 = (const float4*)&ws[(i-32)*3 + 0][o0];
        const float4* w1 = (const float4*)&ws[(i-32)*3 + 1][o0];
        const float4* w2 = (const float4*)&ws[(i-32)*3 + 2][o0];
#pragma unroll
        for (int q = 0; q < 4; ++q) {
            float4 a = w0[q], b = w1[q], c = w2[q];
            acc[q*4+0] = fmaf(a.x, x0, fmaf(b.x, x1, fmaf(c.x, x2, acc[q*4+0])));
            acc[q*4+1] = fmaf(a.y, x0, fmaf(b.y, x1, fmaf(c.y, x2, acc[q*4+1])));
            acc[q*4+2] = fmaf(a.z, x0, fmaf(b.z, x1, fmaf(c.z, x2, acc[q*4+2])));
            acc[q*4+3] = fmaf(a.w, x0, fmaf(b.w, x1, fmaf(c.w, x2, acc[q*4+3])));
        }
    }

    if (!LAST) {
        int Lout = Lin >> 1;
        int j = j0 + lane;
#pragma unroll
        for (int m = 0; m < 16; ++m)
            outp[(o0 + m) * Lout + j] = fmaxf(acc[m], 0.f);
    } else {
#pragma unroll
        for (int m = 0; m < 16; ++m) {
            float v = fmaxf(acc[m], 0.f);
#pragma unroll
            for (int off = 1; off < 64; off <<= 1)
                v = fmaxf(v, __shfl_xor(v, off));
            if (lane == 0) outp[blockIdx.x * 64 + o0 + m] = v;
        }
    }
}

// ---------------------------------------------------------------------------
// Kernel 5: channel max over NB2 block-partials, then the two FCs + sigmoid.
// ---------------------------------------------------------------------------
__global__ __launch_bounds__(64) void fc_k(const float* __restrict__ pmax,
                                           const float* __restrict__ Wf,
                                           const float* __restrict__ bf,
                                           const float* __restrict__ Wp,
                                           const float* __restrict__ bp,
                                           float* __restrict__ out)
{
    __shared__ float cm[64];
    __shared__ float ft[64];
    int t = threadIdx.x;
    float m = 0.f;                       // relu outputs are >= 0
#pragma unroll
    for (int b = 0; b < NB2; ++b) m = fmaxf(m, pmax[b * 64 + t]);
    cm[t] = m;
    __syncthreads();
    float s = bf[t];
#pragma unroll
    for (int c = 0; c < 64; ++c) s = fmaf(Wf[t*64 + c], cm[c], s);
    float f = fmaxf(s, 0.f);
    ft[t] = f;
    out[t] = f;
    __syncthreads();
    if (t == 0) {
        float z = bp[0];
#pragma unroll
        for (int c = 0; c < 64; ++c) z = fmaf(Wp[c], ft[c], z);
        out[64] = 1.f / (1.f + expf(-z));
    }
}

// ---------------------------------------------------------------------------
extern "C" void kernel_launch(void* const* d_in, const int* in_sizes, int n_in,
                              void* d_out, int out_size, void* d_ws, size_t ws_size,
                              hipStream_t stream)
{
    const float* image   = (const float*)d_in[0];
    const float* corners = (const float*)d_in[1];
    const float* W0      = (const float*)d_in[2];
    const float* b0      = (const float*)d_in[3];
    const float* W1      = (const float*)d_in[4];
    const float* b1      = (const float*)d_in[5];
    const float* W2      = (const float*)d_in[6];
    const float* b2      = (const float*)d_in[7];
    const float* Wf      = (const float*)d_in[8];
    const float* bf      = (const float*)d_in[9];
    const float* Wp      = (const float*)d_in[10];
    const float* bp      = (const float*)d_in[11];
    float* out = (float*)d_out;

    // workspace layout (256B-aligned), ~31.9 MB total
    char* w = (char*)d_ws;
    double* el2loc  = (double*)(w);                 //  262144 B
    double* partial = (double*)(w + 262144);        //     512 B
    double* boff    = (double*)(w + 262656);        //     512 B
    float*  pmax    = (float*) (w + 263168);        //   16384 B
    float*  Wt      = (float*) (w + 279552);        //  147456 B
    float*  imgT    = (float*) (w + 427008);        // 16777216 B
    float*  X       = (float*) (w + 17204224);      //  8388608 B
    float*  Y0      = (float*) (w + 25592832);      //  4194304 B
    float*  Y1      = (float*) (w + 29787136);      //  2097152 B -> 31884288

    prep_k        <<<648, 512, 0, stream>>>(corners, W0, W1, W2, image,
                                            el2loc, partial, Wt, imgT);
    scan2_k       <<<1, 64, 0, stream>>>(partial, boff);
    gather_k      <<<NPTS / 256, 256, 0, stream>>>(corners, el2loc, boff, imgT, X);
    conv_k<false> <<<L1 / 64, 256, 0, stream>>>(X,  Wt,         b0, Y0, L0);
    conv_k<false> <<<L2 / 64, 256, 0, stream>>>(Y0, Wt + 12288, b1, Y1, L1);
    conv_k<true>  <<<L3 / 64, 256, 0, stream>>>(Y1, Wt + 24576, b2, pmax, L2);
    fc_k          <<<1, 64, 0, stream>>>(pmax, Wf, bf, Wp, bp, out);
}

// Round 4
// 81.824 us; speedup vs baseline: 1.7375x; 1.0352x over previous
//
#include <hip/hip_runtime.h>
#include <hip/hip_bf16.h>
#include <math.h>

// Problem constants (fixed by setup_inputs)
#define EDGES   32768
#define NPTS    32768
#define IMGH    256
#define L0      32768  // conv0 input length
#define L1      16384
#define L2      8192
#define L3      4096

// ---------------------------------------------------------------------------
// Kernel 1 (fused prep): block-range dispatch, 648 x 512.
//   blocks   0..63  : edge lengths (f64) + in-block inclusive scan of 512
//   blocks  64..135 : weight transpose W[o][i][k] -> Wt[(i*3+k)*64+o] (x3)
//                     (+ block 64 t0 resets the convC ticket counter)
//   blocks 136..647 : image transpose (62,256,256) -> (65536,64), ch 62/63 = 0
// ---------------------------------------------------------------------------
__global__ __launch_bounds__(512) void prep_k(const float* __restrict__ corners,
                                              const float* __restrict__ W0,
                                              const float* __restrict__ W1,
                                              const float* __restrict__ W2,
                                              const float* __restrict__ img,
                                              double* __restrict__ el2loc,
                                              double* __restrict__ partial,
                                              float*  __restrict__ Wt,
                                              float*  __restrict__ imgT,
                                              unsigned* __restrict__ done)
{
    __shared__ union { double sc[512]; float tile[62][129]; } sm;
    int b = blockIdx.x, t = threadIdx.x;
    if (b < 64) {
        int e  = (b << 9) + t;
        int en = (e + 1) & (EDGES - 1);
        double dx = (double)corners[2*en]   - (double)corners[2*e];
        double dy = (double)corners[2*en+1] - (double)corners[2*e+1];
        sm.sc[t] = sqrt(dx*dx + dy*dy);
        __syncthreads();
        for (int o = 1; o < 512; o <<= 1) {        // Hillis-Steele inclusive
            double v = (t >= o) ? sm.sc[t - o] : 0.0;
            __syncthreads();
            sm.sc[t] += v;
            __syncthreads();
        }
        el2loc[e] = sm.sc[t];
        if (t == 511) partial[b] = sm.sc[511];
    } else if (b < 136) {
        if (b == 64 && t == 0) *done = 0u;         // reset convC ticket
        int idx = ((b - 64) << 9) + t;             // < 3*192*64 = 36864
        int l   = idx / 12288;
        int rem = idx - l * 12288;
        int row = rem >> 6, o = rem & 63;
        int i   = row / 3,  k = row - i * 3;
        const float* W = (l == 0) ? W0 : ((l == 1) ? W1 : W2);
        Wt[idx] = W[o*192 + i*3 + k];
    } else {
        int pix0 = (b - 136) << 7;                 // 128 pixels per block
        for (int idx = t; idx < 62*128; idx += 512) {
            int c = idx >> 7, p = idx & 127;
            sm.tile[c][p] = img[c * (IMGH*IMGH) + pix0 + p];
        }
        __syncthreads();
        for (int idx = t; idx < 128*64; idx += 512) {
            int p = idx >> 6, c = idx & 63;
            imgT[(size_t)(pix0 + p) * 64 + c] = (c < 62) ? sm.tile[c][p] : 0.f;
        }
    }
}

// ---------------------------------------------------------------------------
// Kernel 2 (convA): fused point-gather + conv layer 0.
// Block j0 needs input columns [2*j0-1, 2*j0+129): threads 0..129 each
// binary-search their point and gather its imgT row straight into xs;
// threads 130..255 stage weight chunk 0 concurrently. Then the standard
// 64x64 conv compute (weights in LDS, two 96-row chunks).
// ---------------------------------------------------------------------------
__global__ __launch_bounds__(256) void convA_k(const float* __restrict__ corners,
                                               const double* __restrict__ el2loc,
                                               const double* __restrict__ partial,
                                               const float* __restrict__ imgT,
                                               const float* __restrict__ Wt,
                                               const float* __restrict__ bias,
                                               float* __restrict__ Y0)
{
    __shared__ float  xs[64][130];   // 33280 B
    __shared__ float  ws[96][64];    // 24576 B
    __shared__ double sb[64];        //   512 B
    int tid = threadIdx.x;
    int j0  = blockIdx.x << 6;
    int in0 = (j0 << 1) - 1;

    // in-block scan of the 64 edge-chunk partials -> sb (inclusive)
    if (tid < 64) sb[tid] = partial[tid];
    __syncthreads();
#pragma unroll
    for (int o = 1; o < 64; o <<= 1) {
        double v = 0.0;
        if (tid < 64 && tid >= o) v = sb[tid - o];
        __syncthreads();
        if (tid < 64) sb[tid] += v;
        __syncthreads();
    }

    if (tid >= 130) {
        // stage weight chunk 0 (rows 0..95) while gather threads work
        const float4* src = (const float4*)Wt;
        float4*       dst = (float4*)&ws[0][0];
        for (int idx = tid - 130; idx < 96*16; idx += 126) dst[idx] = src[idx];
    } else {
        int g = in0 + tid;                      // point index for this column
        if (g < 0)   g = 1;                     // reflect left
        if (g >= L0) g = 2*L0 - 2 - g;          // guard (halo, value unused)
        double S   = sb[63];
        double off = (double)g * (S * (1.0 / (double)NPTS));
        int lo = 0, hi = EDGES - 1;
        while (lo < hi) {
            int mid = (lo + hi) >> 1;
            double v = el2loc[mid] + ((mid >= 512) ? sb[(mid >> 9) - 1] : 0.0);
            if (v > off) hi = mid; else lo = mid + 1;
        }
        int e = lo;
        double e1 = (e == 0) ? 0.0
                  : el2loc[e-1] + (((e-1) >= 512) ? sb[((e-1) >> 9) - 1] : 0.0);
        float sxf = corners[2*e], syf = corners[2*e+1];
        int en = (e + 1) & (EDGES - 1);
        double dx = (double)corners[2*en]   - (double)sxf;
        double dy = (double)corners[2*en+1] - (double)syf;
        double len = sqrt(dx*dx + dy*dy);
        double t  = (off - e1) / fmax(len, 0.0001);
        double px = (double)sxf + t * dx;
        double py = (double)syf + t * dy;
        int r0 = (int)rint(px * (double)IMGH); r0 = r0 < 0 ? 0 : (r0 > IMGH-1 ? IMGH-1 : r0);
        int r1 = (int)rint(py * (double)IMGH); r1 = r1 < 0 ? 0 : (r1 > IMGH-1 ? IMGH-1 : r1);
        const float*  row  = imgT + (size_t)((r0 << 8) | r1) * 64;
        const float4* row4 = (const float4*)row;
#pragma unroll
        for (int c4 = 0; c4 < 15; ++c4) {       // channels 0..59
            float4 v = row4[c4];
            xs[c4*4 + 0][tid] = v.x;
            xs[c4*4 + 1][tid] = v.y;
            xs[c4*4 + 2][tid] = v.z;
            xs[c4*4 + 3][tid] = v.w;
        }
        xs[60][tid] = row[60];
        xs[61][tid] = row[61];
        xs[62][tid] = (float)px;
        xs[63][tid] = (float)py;
    }
    __syncthreads();

    int lane = tid & 63;
    int o0   = (tid >> 6) << 4;
    float acc[16];
#pragma unroll
    for (int m = 0; m < 16; ++m) acc[m] = bias[o0 + m];

    int jl2 = lane << 1;
#pragma unroll 4
    for (int i = 0; i < 32; ++i) {
        float x0 = xs[i][jl2], x1 = xs[i][jl2 + 1], x2 = xs[i][jl2 + 2];
        const float4* w0 = (const float4*)&ws[i*3 + 0][o0];
        const float4* w1 = (const float4*)&ws[i*3 + 1][o0];
        const float4* w2 = (const float4*)&ws[i*3 + 2][o0];
#pragma unroll
        for (int q = 0; q < 4; ++q) {
            float4 a = w0[q], b = w1[q], c = w2[q];
            acc[q*4+0] = fmaf(a.x, x0, fmaf(b.x, x1, fmaf(c.x, x2, acc[q*4+0])));
            acc[q*4+1] = fmaf(a.y, x0, fmaf(b.y, x1, fmaf(c.y, x2, acc[q*4+1])));
            acc[q*4+2] = fmaf(a.z, x0, fmaf(b.z, x1, fmaf(c.z, x2, acc[q*4+2])));
            acc[q*4+3] = fmaf(a.w, x0, fmaf(b.w, x1, fmaf(c.w, x2, acc[q*4+3])));
        }
    }
    __syncthreads();
    {   // weight chunk 1 (rows 96..191)
        const float4* src = ((const float4*)Wt) + 96*16;
        float4*       dst = (float4*)&ws[0][0];
        for (int idx = tid; idx < 96*16; idx += 256) dst[idx] = src[idx];
    }
    __syncthreads();
#pragma unroll 4
    for (int i = 32; i < 64; ++i) {
        float x0 = xs[i][jl2], x1 = xs[i][jl2 + 1], x2 = xs[i][jl2 + 2];
        const float4* w0 = (const float4*)&ws[(i-32)*3 + 0][o0];
        const float4* w1 = (const float4*)&ws[(i-32)*3 + 1][o0];
        const float4* w2 = (const float4*)&ws[(i-32)*3 + 2][o0];
#pragma unroll
        for (int q = 0; q < 4; ++q) {
            float4 a = w0[q], b = w1[q], c = w2[q];
            acc[q*4+0] = fmaf(a.x, x0, fmaf(b.x, x1, fmaf(c.x, x2, acc[q*4+0])));
            acc[q*4+1] = fmaf(a.y, x0, fmaf(b.y, x1, fmaf(c.y, x2, acc[q*4+1])));
            acc[q*4+2] = fmaf(a.z, x0, fmaf(b.z, x1, fmaf(c.z, x2, acc[q*4+2])));
            acc[q*4+3] = fmaf(a.w, x0, fmaf(b.w, x1, fmaf(c.w, x2, acc[q*4+3])));
        }
    }
    int j = j0 + lane;
#pragma unroll
    for (int m = 0; m < 16; ++m)
        Y0[(o0 + m) * L1 + j] = fmaxf(acc[m], 0.f);
}

// ---------------------------------------------------------------------------
// Kernel 3 (convB): conv layer 1 (Y0 -> Y1), weights in LDS, same scheme.
// ---------------------------------------------------------------------------
__global__ __launch_bounds__(256) void convB_k(const float* __restrict__ Xin,
                                               const float* __restrict__ Wt,
                                               const float* __restrict__ bias,
                                               float* __restrict__ Yout,
                                               int Lin)
{
    __shared__ float xs[64][130];
    __shared__ float ws[96][64];
    int tid = threadIdx.x;
    int j0  = blockIdx.x << 6;
    int in0 = (j0 << 1) - 1;
    for (int idx = tid; idx < 64 * 130; idx += 256) {
        int i  = idx / 130;
        int pp = idx - i * 130;
        int g  = in0 + pp;
        if (g < 0)    g = 1;
        if (g >= Lin) g = 2 * Lin - 2 - g;
        xs[i][pp] = Xin[i * Lin + g];
    }
    {
        const float4* src = (const float4*)Wt;
        float4*       dst = (float4*)&ws[0][0];
        for (int idx = tid; idx < 96*16; idx += 256) dst[idx] = src[idx];
    }
    __syncthreads();

    int lane = tid & 63;
    int o0   = (tid >> 6) << 4;
    float acc[16];
#pragma unroll
    for (int m = 0; m < 16; ++m) acc[m] = bias[o0 + m];
    int jl2 = lane << 1;
#pragma unroll 4
    for (int i = 0; i < 32; ++i) {
        float x0 = xs[i][jl2], x1 = xs[i][jl2 + 1], x2 = xs[i][jl2 + 2];
        const float4* w0 = (const float4*)&ws[i*3 + 0][o0];
        const float4* w1 = (const float4*)&ws[i*3 + 1][o0];
        const float4* w2 = (const float4*)&ws[i*3 + 2][o0];
#pragma unroll
        for (int q = 0; q < 4; ++q) {
            float4 a = w0[q], b = w1[q], c = w2[q];
            acc[q*4+0] = fmaf(a.x, x0, fmaf(b.x, x1, fmaf(c.x, x2, acc[q*4+0])));
            acc[q*4+1] = fmaf(a.y, x0, fmaf(b.y, x1, fmaf(c.y, x2, acc[q*4+1])));
            acc[q*4+2] = fmaf(a.z, x0, fmaf(b.z, x1, fmaf(c.z, x2, acc[q*4+2])));
            acc[q*4+3] = fmaf(a.w, x0, fmaf(b.w, x1, fmaf(c.w, x2, acc[q*4+3])));
        }
    }
    __syncthreads();
    {
        const float4* src = ((const float4*)Wt) + 96*16;
        float4*       dst = (float4*)&ws[0][0];
        for (int idx = tid; idx < 96*16; idx += 256) dst[idx] = src[idx];
    }
    __syncthreads();
#pragma unroll 4
    for (int i = 32; i < 64; ++i) {
        float x0 = xs[i][jl2], x1 = xs[i][jl2 + 1], x2 = xs[i][jl2 + 2];
        const float4* w0 = (const float4*)&ws[(i-32)*3 + 0][o0];
        const float4* w1 = (const float4*)&ws[(i-32)*3 + 1][o0];
        const float4* w2 = (const float4*)&ws[(i-32)*3 + 2][o0];
#pragma unroll
        for (int q = 0; q < 4; ++q) {
            float4 a = w0[q], b = w1[q], c = w2[q];
            acc[q*4+0] = fmaf(a.x, x0, fmaf(b.x, x1, fmaf(c.x, x2, acc[q*4+0])));
            acc[q*4+1] = fmaf(a.y, x0, fmaf(b.y, x1, fmaf(c.y, x2, acc[q*4+1])));
            acc[q*4+2] = fmaf(a.z, x0, fmaf(b.z, x1, fmaf(c.z, x2, acc[q*4+2])));
            acc[q*4+3] = fmaf(a.w, x0, fmaf(b.w, x1, fmaf(c.w, x2, acc[q*4+3])));
        }
    }
    int Lout = Lin >> 1;
    int j = j0 + lane;
#pragma unroll
    for (int m = 0; m < 16; ++m)
        Yout[(o0 + m) * Lout + j] = fmaxf(acc[m], 0.f);
}

// ---------------------------------------------------------------------------
// Kernel 4 (convC): conv layer 2 + per-block channel max -> pmax; the LAST
// block to finish (ticket counter) reduces pmax and runs the two FCs.
// ---------------------------------------------------------------------------
__global__ __launch_bounds__(256) void convC_k(const float* __restrict__ Xin,
                                               const float* __restrict__ Wt,
                                               const float* __restrict__ bias,
                                               const float* __restrict__ Wf,
                                               const float* __restrict__ bf,
                                               const float* __restrict__ Wp,
                                               const float* __restrict__ bp,
                                               float* __restrict__ pmax,
                                               unsigned* __restrict__ done,
                                               float* __restrict__ out)
{
    __shared__ float xs[64][130];
    __shared__ float ws[96][64];
    __shared__ float cm[64];
    __shared__ float ft[64];
    __shared__ unsigned ticket;
    const int Lin = L2;
    int tid = threadIdx.x;
    int j0  = blockIdx.x << 6;
    int in0 = (j0 << 1) - 1;
    for (int idx = tid; idx < 64 * 130; idx += 256) {
        int i  = idx / 130;
        int pp = idx - i * 130;
        int g  = in0 + pp;
        if (g < 0)    g = 1;
        if (g >= Lin) g = 2 * Lin - 2 - g;
        xs[i][pp] = Xin[i * Lin + g];
    }
    {
        const float4* src = (const float4*)Wt;
        float4*       dst = (float4*)&ws[0][0];
        for (int idx = tid; idx < 96*16; idx += 256) dst[idx] = src[idx];
    }
    __syncthreads();

    int lane = tid & 63;
    int o0   = (tid >> 6) << 4;
    float acc[16];
#pragma unroll
    for (int m = 0; m < 16; ++m) acc[m] = bias[o0 + m];
    int jl2 = lane << 1;
#pragma unroll 4
    for (int i = 0; i < 32; ++i) {
        float x0 = xs[i][jl2], x1 = xs[i][jl2 + 1], x2 = xs[i][jl2 + 2];
        const float4* w0 = (const float4*)&ws[i*3 + 0][o0];
        const float4* w1 = (const float4*)&ws[i*3 + 1][o0];
        const float4* w2 = (const float4*)&ws[i*3 + 2][o0];
#pragma unroll
        for (int q = 0; q < 4; ++q) {
            float4 a = w0[q], b = w1[q], c = w2[q];
            acc[q*4+0] = fmaf(a.x, x0, fmaf(b.x, x1, fmaf(c.x, x2, acc[q*4+0])));
            acc[q*4+1] = fmaf(a.y, x0, fmaf(b.y, x1, fmaf(c.y, x2, acc[q*4+1])));
            acc[q*4+2] = fmaf(a.z, x0, fmaf(b.z, x1, fmaf(c.z, x2, acc[q*4+2])));
            acc[q*4+3] = fmaf(a.w, x0, fmaf(b.w, x1, fmaf(c.w, x2, acc[q*4+3])));
        }
    }
    __syncthreads();
    {
        const float4* src = ((const float4*)Wt) + 96*16;
        float4*       dst = (float4*)&ws[0][0];
        for (int idx = tid; idx < 96*16; idx += 256) dst[idx] = src[idx];
    }
    __syncthreads();
#pragma unroll 4
    for (int i = 32; i < 64; ++i) {
        float x0 = xs[i][jl2], x1 = xs[i][jl2 + 1], x2 = xs[i][jl2 + 2];
        const float4* w0 = (const float4*)&ws[(i-32)*3 + 0][o0];
        const float4* w1 = (const float4*)&ws[(i-32)*3 + 1][o0];
        const float4* w2 = (const float4*)&ws[(i-32)*3 + 2][o0];
#pragma unroll
        for (int q = 0; q < 4; ++q) {
            float4 a = w0[q], b = w1[q], c = w2[q];
            acc[q*4+0] = fmaf(a.x, x0, fmaf(b.x, x1, fmaf(c.x, x2, acc[q*4+0])));
            acc[q*4+1] = fmaf(a.y, x0, fmaf(b.y, x1, fmaf(c.y, x2, acc[q*4+1])));
            acc[q*4+2] = fmaf(a.z, x0, fmaf(b.z, x1, fmaf(c.z, x2, acc[q*4+2])));
            acc[q*4+3] = fmaf(a.w, x0, fmaf(b.w, x1, fmaf(c.w, x2, acc[q*4+3])));
        }
    }
    // per-block channel max -> pmax[block*64 + ch]
#pragma unroll
    for (int m = 0; m < 16; ++m) {
        float v = fmaxf(acc[m], 0.f);
#pragma unroll
        for (int off = 1; off < 64; off <<= 1)
            v = fmaxf(v, __shfl_xor(v, off));
        if (lane == 0) pmax[blockIdx.x * 64 + o0 + m] = v;
    }
    __threadfence();
    __syncthreads();
    if (tid == 0) ticket = atomicAdd(done, 1u);
    __syncthreads();
    if (ticket == 63) {                  // last block: channel max + FCs
        __threadfence();
        if (tid < 64) {
            float m = 0.f;               // relu outputs >= 0
#pragma unroll
            for (int b = 0; b < 64; ++b) m = fmaxf(m, pmax[b * 64 + tid]);
            cm[tid] = m;
        }
        __syncthreads();
        if (tid < 64) {
            float s = bf[tid];
#pragma unroll
            for (int c = 0; c < 64; ++c) s = fmaf(Wf[tid*64 + c], cm[c], s);
            float f = fmaxf(s, 0.f);
            ft[tid] = f;
            out[tid] = f;
        }
        __syncthreads();
        if (tid == 0) {
            float z = bp[0];
#pragma unroll
            for (int c = 0; c < 64; ++c) z = fmaf(Wp[c], ft[c], z);
            out[64] = 1.f / (1.f + expf(-z));
        }
    }
}

// ---------------------------------------------------------------------------
extern "C" void kernel_launch(void* const* d_in, const int* in_sizes, int n_in,
                              void* d_out, int out_size, void* d_ws, size_t ws_size,
                              hipStream_t stream)
{
    const float* image   = (const float*)d_in[0];
    const float* corners = (const float*)d_in[1];
    const float* W0      = (const float*)d_in[2];
    const float* b0      = (const float*)d_in[3];
    const float* W1      = (const float*)d_in[4];
    const float* b1      = (const float*)d_in[5];
    const float* W2      = (const float*)d_in[6];
    const float* b2      = (const float*)d_in[7];
    const float* Wf      = (const float*)d_in[8];
    const float* bf      = (const float*)d_in[9];
    const float* Wp      = (const float*)d_in[10];
    const float* bp      = (const float*)d_in[11];
    float* out = (float*)d_out;

    // workspace layout (256B-aligned), ~23.5 MB total
    char* w = (char*)d_ws;
    double*   el2loc  = (double*)  (w);              //   262144 B
    double*   partial = (double*)  (w + 262144);     //      512 B
    unsigned* done    = (unsigned*)(w + 262656);     //      256 B
    float*    pmax    = (float*)   (w + 262912);     //    16384 B
    float*    Wt      = (float*)   (w + 279296);     //   147456 B
    float*    imgT    = (float*)   (w + 426752);     // 16777216 B
    float*    Y0      = (float*)   (w + 17203968);   //  4194304 B
    float*    Y1      = (float*)   (w + 21398272);   //  2097152 B -> 23495424

    prep_k  <<<648, 512, 0, stream>>>(corners, W0, W1, W2, image,
                                      el2loc, partial, Wt, imgT, done);
    convA_k <<<L1 / 64, 256, 0, stream>>>(corners, el2loc, partial, imgT,
                                          Wt, b0, Y0);
    convB_k <<<L2 / 64, 256, 0, stream>>>(Y0, Wt + 12288, b1, Y1, L1);
    convC_k <<<L3 / 64, 256, 0, stream>>>(Y1, Wt + 24576, b2,
                                          Wf, bf, Wp, bp, pmax, done, out);
}

// Round 5
// 69.895 us; speedup vs baseline: 2.0340x; 1.1707x over previous
//
#include <hip/hip_runtime.h>
#include <hip/hip_bf16.h>
#include <math.h>

// Problem constants (fixed by setup_inputs)
#define EDGES   32768
#define NPTS    32768
#define IMGH    256
#define L0      32768  // conv0 input length
#define L1      16384
#define L2      8192
#define L3      4096

// ---------------------------------------------------------------------------
// Kernel 1 (fused prep): block-range dispatch, 648 x 512.
//   blocks   0..63  : edge lengths (f64) + in-block inclusive scan of 512
//   blocks  64..135 : weight transpose W[o][i][k] -> Wt[(i*3+k)*64+o] (x3)
//                     (+ block 64 t0 resets the convC ticket counter)
//   blocks 136..647 : image transpose (62,256,256) -> (65536,64), ch 62/63 = 0
// ---------------------------------------------------------------------------
__global__ __launch_bounds__(512) void prep_k(const float* __restrict__ corners,
                                              const float* __restrict__ W0,
                                              const float* __restrict__ W1,
                                              const float* __restrict__ W2,
                                              const float* __restrict__ img,
                                              double* __restrict__ el2loc,
                                              double* __restrict__ partial,
                                              float*  __restrict__ Wt,
                                              float*  __restrict__ imgT,
                                              unsigned* __restrict__ done)
{
    __shared__ union { double sc[512]; float tile[62][129]; } sm;
    int b = blockIdx.x, t = threadIdx.x;
    if (b < 64) {
        int e  = (b << 9) + t;
        int en = (e + 1) & (EDGES - 1);
        double dx = (double)corners[2*en]   - (double)corners[2*e];
        double dy = (double)corners[2*en+1] - (double)corners[2*e+1];
        sm.sc[t] = sqrt(dx*dx + dy*dy);
        __syncthreads();
        for (int o = 1; o < 512; o <<= 1) {        // Hillis-Steele inclusive
            double v = (t >= o) ? sm.sc[t - o] : 0.0;
            __syncthreads();
            sm.sc[t] += v;
            __syncthreads();
        }
        el2loc[e] = sm.sc[t];
        if (t == 511) partial[b] = sm.sc[511];
    } else if (b < 136) {
        if (b == 64 && t == 0) *done = 0u;         // reset convC ticket
        int idx = ((b - 64) << 9) + t;             // < 3*192*64 = 36864
        int l   = idx / 12288;
        int rem = idx - l * 12288;
        int row = rem >> 6, o = rem & 63;
        int i   = row / 3,  k = row - i * 3;
        const float* W = (l == 0) ? W0 : ((l == 1) ? W1 : W2);
        Wt[idx] = W[o*192 + i*3 + k];
    } else {
        int pix0 = (b - 136) << 7;                 // 128 pixels per block
        for (int idx = t; idx < 62*128; idx += 512) {
            int c = idx >> 7, p = idx & 127;
            sm.tile[c][p] = img[c * (IMGH*IMGH) + pix0 + p];
        }
        __syncthreads();
        for (int idx = t; idx < 128*64; idx += 512) {
            int p = idx >> 6, c = idx & 63;
            imgT[(size_t)(pix0 + p) * 64 + c] = (c < 62) ? sm.tile[c][p] : 0.f;
        }
    }
}

// ---------------------------------------------------------------------------
// Batched x-tile staging: 64 rows x 130 cols from Xin (reflect left halo),
// 32 fully-unrolled independent loads per thread + 128-elem tail, THEN the
// LDS writes. One memory latency instead of 33 serialized round-trips.
// ---------------------------------------------------------------------------
__device__ __forceinline__ void stage_xs(float xs[64][130],
                                         const float* __restrict__ Xin,
                                         int in0, int Lin, int tid)
{
    float r[32];
#pragma unroll
    for (int k = 0; k < 32; ++k) {
        int idx = k * 256 + tid;
        int i   = idx / 130;
        int pp  = idx - i * 130;
        int g   = in0 + pp;
        if (g < 0)    g = 1;
        if (g >= Lin) g = 2 * Lin - 2 - g;
        r[k] = Xin[i * Lin + g];
    }
    float rt = 0.f;
    if (tid < 128) {                       // tail: idx 8192..8319 (row 63)
        int pp = 2 + tid;
        int g  = in0 + pp;
        if (g < 0)    g = 1;
        if (g >= Lin) g = 2 * Lin - 2 - g;
        rt = Xin[63 * Lin + g];
    }
#pragma unroll
    for (int k = 0; k < 32; ++k) {
        int idx = k * 256 + tid;
        int i   = idx / 130;
        int pp  = idx - i * 130;
        xs[i][pp] = r[k];
    }
    if (tid < 128) xs[63][2 + tid] = rt;
}

// Batched weight-chunk staging: 96 rows x 64 ch = 1536 float4, 6 per thread.
__device__ __forceinline__ void stage_ws(float ws[96][64],
                                         const float* __restrict__ Wsrc,
                                         int tid)
{
    const float4* src = (const float4*)Wsrc;
    float4 rw[6];
#pragma unroll
    for (int k = 0; k < 6; ++k) rw[k] = src[k * 256 + tid];
    float4* dst = (float4*)&ws[0][0];
#pragma unroll
    for (int k = 0; k < 6; ++k) dst[k * 256 + tid] = rw[k];
}

// The 64x64 k=3 stride-2 conv compute on a staged half (32 input rows).
__device__ __forceinline__ void conv_half(float acc[16],
                                          const float xs[64][130],
                                          const float ws[96][64],
                                          int ibase, int jl2, int o0)
{
#pragma unroll 4
    for (int ii = 0; ii < 32; ++ii) {
        int i = ibase + ii;
        float x0 = xs[i][jl2], x1 = xs[i][jl2 + 1], x2 = xs[i][jl2 + 2];
        const float4* w0 = (const float4*)&ws[ii*3 + 0][o0];
        const float4* w1 = (const float4*)&ws[ii*3 + 1][o0];
        const float4* w2 = (const float4*)&ws[ii*3 + 2][o0];
#pragma unroll
        for (int q = 0; q < 4; ++q) {
            float4 a = w0[q], b = w1[q], c = w2[q];
            acc[q*4+0] = fmaf(a.x, x0, fmaf(b.x, x1, fmaf(c.x, x2, acc[q*4+0])));
            acc[q*4+1] = fmaf(a.y, x0, fmaf(b.y, x1, fmaf(c.y, x2, acc[q*4+1])));
            acc[q*4+2] = fmaf(a.z, x0, fmaf(b.z, x1, fmaf(c.z, x2, acc[q*4+2])));
            acc[q*4+3] = fmaf(a.w, x0, fmaf(b.w, x1, fmaf(c.w, x2, acc[q*4+3])));
        }
    }
}

// ---------------------------------------------------------------------------
// Kernel 2 (convA): fused point-gather + conv layer 0.
// ---------------------------------------------------------------------------
__global__ __launch_bounds__(256) void convA_k(const float* __restrict__ corners,
                                               const double* __restrict__ el2loc,
                                               const double* __restrict__ partial,
                                               const float* __restrict__ imgT,
                                               const float* __restrict__ Wt,
                                               const float* __restrict__ bias,
                                               float* __restrict__ Y0)
{
    __shared__ float  xs[64][130];   // 33280 B
    __shared__ float  ws[96][64];    // 24576 B
    __shared__ double sb[64];        //   512 B
    int tid = threadIdx.x;
    int j0  = blockIdx.x << 6;
    int in0 = (j0 << 1) - 1;

    // in-block scan of the 64 edge-chunk partials -> sb (inclusive)
    if (tid < 64) sb[tid] = partial[tid];
    __syncthreads();
#pragma unroll
    for (int o = 1; o < 64; o <<= 1) {
        double v = 0.0;
        if (tid < 64 && tid >= o) v = sb[tid - o];
        __syncthreads();
        if (tid < 64) sb[tid] += v;
        __syncthreads();
    }

    stage_ws(ws, Wt, tid);                 // chunk 0, batched, all threads

    if (tid < 130) {
        int g = in0 + tid;                 // point index for this column
        if (g < 0)   g = 1;                // reflect left
        if (g >= L0) g = 2*L0 - 2 - g;     // guard (halo, value unused)
        double S   = sb[63];
        double off = (double)g * (S * (1.0 / (double)NPTS));
        // two-level lower_bound: chunk via sb (LDS), then within 512 edges.
        int clo = 0, chi = 63;
        while (clo < chi) {
            int cm = (clo + chi) >> 1;
            if (sb[cm] > off) chi = cm; else clo = cm + 1;
        }
        double base = (clo == 0) ? 0.0 : sb[clo - 1];
        int lo = clo << 9, hi = lo + 511;
        while (lo < hi) {
            int mid = (lo + hi) >> 1;
            if (el2loc[mid] + base > off) hi = mid; else lo = mid + 1;
        }
        int e = lo;
        double e1 = (e == 0) ? 0.0
                  : el2loc[e-1] + (((e-1) >= 512) ? sb[((e-1) >> 9) - 1] : 0.0);
        float sxf = corners[2*e], syf = corners[2*e+1];
        int en = (e + 1) & (EDGES - 1);
        double dx = (double)corners[2*en]   - (double)sxf;
        double dy = (double)corners[2*en+1] - (double)syf;
        double len = sqrt(dx*dx + dy*dy);
        double t  = (off - e1) / fmax(len, 0.0001);
        double px = (double)sxf + t * dx;
        double py = (double)syf + t * dy;
        int r0 = (int)rint(px * (double)IMGH); r0 = r0 < 0 ? 0 : (r0 > IMGH-1 ? IMGH-1 : r0);
        int r1 = (int)rint(py * (double)IMGH); r1 = r1 < 0 ? 0 : (r1 > IMGH-1 ? IMGH-1 : r1);
        const float*  row  = imgT + (size_t)((r0 << 8) | r1) * 64;
        const float4* row4 = (const float4*)row;
        float4 rv[15];
#pragma unroll
        for (int c4 = 0; c4 < 15; ++c4) rv[c4] = row4[c4];   // batched loads
        float c60 = row[60], c61 = row[61];
#pragma unroll
        for (int c4 = 0; c4 < 15; ++c4) {
            xs[c4*4 + 0][tid] = rv[c4].x;
            xs[c4*4 + 1][tid] = rv[c4].y;
            xs[c4*4 + 2][tid] = rv[c4].z;
            xs[c4*4 + 3][tid] = rv[c4].w;
        }
        xs[60][tid] = c60;
        xs[61][tid] = c61;
        xs[62][tid] = (float)px;
        xs[63][tid] = (float)py;
    }
    __syncthreads();

    int lane = tid & 63;
    int o0   = (tid >> 6) << 4;
    float acc[16];
#pragma unroll
    for (int m = 0; m < 16; ++m) acc[m] = bias[o0 + m];
    int jl2 = lane << 1;

    conv_half(acc, xs, ws, 0, jl2, o0);
    __syncthreads();
    stage_ws(ws, Wt + 96*64, tid);         // chunk 1
    __syncthreads();
    conv_half(acc, xs, ws, 32, jl2, o0);

    int j = j0 + lane;
#pragma unroll
    for (int m = 0; m < 16; ++m)
        Y0[(o0 + m) * L1 + j] = fmaxf(acc[m], 0.f);
}

// ---------------------------------------------------------------------------
// Kernel 3 (convB): conv layer 1 (Y0 -> Y1), batched staging.
// ---------------------------------------------------------------------------
__global__ __launch_bounds__(256) void convB_k(const float* __restrict__ Xin,
                                               const float* __restrict__ Wt,
                                               const float* __restrict__ bias,
                                               float* __restrict__ Yout,
                                               int Lin)
{
    __shared__ float xs[64][130];
    __shared__ float ws[96][64];
    int tid = threadIdx.x;
    int j0  = blockIdx.x << 6;
    int in0 = (j0 << 1) - 1;

    stage_xs(xs, Xin, in0, Lin, tid);
    stage_ws(ws, Wt, tid);
    __syncthreads();

    int lane = tid & 63;
    int o0   = (tid >> 6) << 4;
    float acc[16];
#pragma unroll
    for (int m = 0; m < 16; ++m) acc[m] = bias[o0 + m];
    int jl2 = lane << 1;

    conv_half(acc, xs, ws, 0, jl2, o0);
    __syncthreads();
    stage_ws(ws, Wt + 96*64, tid);
    __syncthreads();
    conv_half(acc, xs, ws, 32, jl2, o0);

    int Lout = Lin >> 1;
    int j = j0 + lane;
#pragma unroll
    for (int m = 0; m < 16; ++m)
        Yout[(o0 + m) * Lout + j] = fmaxf(acc[m], 0.f);
}

// ---------------------------------------------------------------------------
// Kernel 4 (convC): conv layer 2 + per-block channel max -> pmax; the LAST
// block to finish (ticket counter) reduces pmax and runs the two FCs.
// ---------------------------------------------------------------------------
__global__ __launch_bounds__(256) void convC_k(const float* __restrict__ Xin,
                                               const float* __restrict__ Wt,
                                               const float* __restrict__ bias,
                                               const float* __restrict__ Wf,
                                               const float* __restrict__ bf,
                                               const float* __restrict__ Wp,
                                               const float* __restrict__ bp,
                                               float* __restrict__ pmax,
                                               unsigned* __restrict__ done,
                                               float* __restrict__ out)
{
    __shared__ float xs[64][130];
    __shared__ float ws[96][64];
    __shared__ float cm[64];
    __shared__ float ft[64];
    __shared__ unsigned ticket;
    const int Lin = L2;
    int tid = threadIdx.x;
    int j0  = blockIdx.x << 6;
    int in0 = (j0 << 1) - 1;

    stage_xs(xs, Xin, in0, Lin, tid);
    stage_ws(ws, Wt, tid);
    __syncthreads();

    int lane = tid & 63;
    int o0   = (tid >> 6) << 4;
    float acc[16];
#pragma unroll
    for (int m = 0; m < 16; ++m) acc[m] = bias[o0 + m];
    int jl2 = lane << 1;

    conv_half(acc, xs, ws, 0, jl2, o0);
    __syncthreads();
    stage_ws(ws, Wt + 96*64, tid);
    __syncthreads();
    conv_half(acc, xs, ws, 32, jl2, o0);

    // per-block channel max -> pmax[block*64 + ch]
#pragma unroll
    for (int m = 0; m < 16; ++m) {
        float v = fmaxf(acc[m], 0.f);
#pragma unroll
        for (int off = 1; off < 64; off <<= 1)
            v = fmaxf(v, __shfl_xor(v, off));
        if (lane == 0) pmax[blockIdx.x * 64 + o0 + m] = v;
    }
    __threadfence();
    __syncthreads();
    if (tid == 0) ticket = atomicAdd(done, 1u);
    __syncthreads();
    if (ticket == 63) {                  // last block: channel max + FCs
        __threadfence();
        if (tid < 64) {
            float m = 0.f;               // relu outputs >= 0
#pragma unroll
            for (int b = 0; b < 64; ++b) m = fmaxf(m, pmax[b * 64 + tid]);
            cm[tid] = m;
        }
        __syncthreads();
        if (tid < 64) {
            float s = bf[tid];
#pragma unroll
            for (int c = 0; c < 64; ++c) s = fmaf(Wf[tid*64 + c], cm[c], s);
            float f = fmaxf(s, 0.f);
            ft[tid] = f;
            out[tid] = f;
        }
        __syncthreads();
        if (tid == 0) {
            float z = bp[0];
#pragma unroll
            for (int c = 0; c < 64; ++c) z = fmaf(Wp[c], ft[c], z);
            out[64] = 1.f / (1.f + expf(-z));
        }
    }
}

// ---------------------------------------------------------------------------
extern "C" void kernel_launch(void* const* d_in, const int* in_sizes, int n_in,
                              void* d_out, int out_size, void* d_ws, size_t ws_size,
                              hipStream_t stream)
{
    const float* image   = (const float*)d_in[0];
    const float* corners = (const float*)d_in[1];
    const float* W0      = (const float*)d_in[2];
    const float* b0      = (const float*)d_in[3];
    const float* W1      = (const float*)d_in[4];
    const float* b1      = (const float*)d_in[5];
    const float* W2      = (const float*)d_in[6];
    const float* b2      = (const float*)d_in[7];
    const float* Wf      = (const float*)d_in[8];
    const float* bf      = (const float*)d_in[9];
    const float* Wp      = (const float*)d_in[10];
    const float* bp      = (const float*)d_in[11];
    float* out = (float*)d_out;

    // workspace layout (256B-aligned), ~23.5 MB total
    char* w = (char*)d_ws;
    double*   el2loc  = (double*)  (w);              //   262144 B
    double*   partial = (double*)  (w + 262144);     //      512 B
    unsigned* done    = (unsigned*)(w + 262656);     //      256 B
    float*    pmax    = (float*)   (w + 262912);     //    16384 B
    float*    Wt      = (float*)   (w + 279296);     //   147456 B
    float*    imgT    = (float*)   (w + 426752);     // 16777216 B
    float*    Y0      = (float*)   (w + 17203968);   //  4194304 B
    float*    Y1      = (float*)   (w + 21398272);   //  2097152 B -> 23495424

    prep_k  <<<648, 512, 0, stream>>>(corners, W0, W1, W2, image,
                                      el2loc, partial, Wt, imgT, done);
    convA_k <<<L1 / 64, 256, 0, stream>>>(corners, el2loc, partial, imgT,
                                          Wt, b0, Y0);
    convB_k <<<L2 / 64, 256, 0, stream>>>(Y0, Wt + 12288, b1, Y1, L1);
    convC_k <<<L3 / 64, 256, 0, stream>>>(Y1, Wt + 24576, b2,
                                          Wf, bf, Wp, bp, pmax, done, out);
}